// Round 3
// baseline (114.399 us; speedup 1.0000x reference)
//
#include <hip/hip_runtime.h>
#include <hip/hip_fp16.h>
#include <math.h>

constexpr int D     = 1024;
constexpr int NEXP  = 4;
constexpr int TOPK  = 32;
constexpr int EPP   = 2048;   // entries per expert
constexpr int TB    = 8;      // tokens per block in attention phase

// packed-half type exactly as the builtins define it
using pk_t = decltype(__builtin_amdgcn_cvt_pkrtz(0.f, 0.f));

__device__ __forceinline__ unsigned pk2(float a, float b) {
    pk_t h = __builtin_amdgcn_cvt_pkrtz(a, b);
    return __builtin_bit_cast(unsigned, h);
}
__device__ __forceinline__ __half2 as_hh2(unsigned u) { return __builtin_bit_cast(__half2, u); }

#if __has_builtin(__builtin_amdgcn_fdot2)
__device__ __forceinline__ float fdot2u(unsigned a, unsigned b, float c) {
    return __builtin_amdgcn_fdot2(__builtin_bit_cast(pk_t, a),
                                  __builtin_bit_cast(pk_t, b), c, false);
}
#else
__device__ __forceinline__ float fdot2u(unsigned a, unsigned b, float c) {
    __half2 ha = as_hh2(a), hb = as_hh2(b);
    return c + __low2float(ha) * __low2float(hb) + __high2float(ha) * __high2float(hb);
}
#endif

// ---------------- Phase 1: router (one wave per token) ----------------
__global__ __launch_bounds__(256) void router_kernel(
    const float* __restrict__ h,
    const float* __restrict__ Wr,
    const float* __restrict__ br,
    float* __restrict__ out_ew,
    int* __restrict__ cnt,
    int* __restrict__ list,
    int ntok)
{
    const int tid  = threadIdx.x;
    const int wid  = tid >> 6;
    const int lane = tid & 63;
    const int tok  = blockIdx.x * 4 + wid;
    if (tok >= ntok) return;

    const float4* h4 = reinterpret_cast<const float4*>(h);
    const float4* w4 = reinterpret_cast<const float4*>(Wr);

    float acc[NEXP] = {0.f, 0.f, 0.f, 0.f};
    #pragma unroll
    for (int i = 0; i < 4; ++i) {
        const float4 a = h4[(size_t)tok * 256 + lane + 64 * i];
        #pragma unroll
        for (int e = 0; e < NEXP; ++e) {
            const float4 w = w4[e * 256 + lane + 64 * i];
            acc[e] += a.x * w.x + a.y * w.y + a.z * w.z + a.w * w.w;
        }
    }
    #pragma unroll
    for (int m = 1; m < 64; m <<= 1) {
        #pragma unroll
        for (int e = 0; e < NEXP; ++e) acc[e] += __shfl_xor(acc[e], m);
    }
    float l0 = acc[0] + br[0], l1 = acc[1] + br[1],
          l2 = acc[2] + br[2], l3 = acc[3] + br[3];

    // softmax (f32, max-subtracted) -> expert_weights
    const float lm = fmaxf(fmaxf(l0, l1), fmaxf(l2, l3));
    const float e0 = __expf(l0 - lm), e1 = __expf(l1 - lm),
                e2 = __expf(l2 - lm), e3 = __expf(l3 - lm);
    const float einv = 1.f / (e0 + e1 + e2 + e3);
    if (lane < NEXP) {
        const float ev = (lane == 0) ? e0 : (lane == 1) ? e1 : (lane == 2) ? e2 : e3;
        out_ew[(size_t)tok * NEXP + lane] = ev * einv;
    }

    // argmax, first-max tie semantics
    int bi = 0; float bv = l0;
    if (l1 > bv) { bv = l1; bi = 1; }
    if (l2 > bv) { bv = l2; bi = 2; }
    if (l3 > bv) { bv = l3; bi = 3; }

    if (lane == 0) {
        const int pos = atomicAdd(&cnt[bi], 1);
        list[bi * ntok + pos] = tok;
    }
}

// ---------------- Phase 2: grouped attention ----------------
// grid = NEXP * chunks blocks; block = 256 threads (4 waves), TB tokens,
// 2 tokens per wave. Slice staged once per block in LDS as f16x2.
__global__ __launch_bounds__(256) void attn_kernel(
    const float* __restrict__ h,
    const float* __restrict__ lts,
    const int* __restrict__ cnt,
    const int* __restrict__ list,
    float* __restrict__ out_res,
    int ntok, int chunks)
{
    const int e     = blockIdx.x / chunks;
    const int chunk = blockIdx.x - e * chunks;
    const int n_e   = cnt[e];
    const int base  = chunk * TB;
    if (base >= n_e) return;   // uniform per block

    const int tid = threadIdx.x;
    __shared__ uint4 sh4[32 * 128];           // [32 rows][512 f16x2] = 64 KB

    // ---- stage slice e (rows e*EPP .. +31), f32 -> f16x2, coalesced ----
    {
        const float4* src = reinterpret_cast<const float4*>(lts + (size_t)e * EPP * D);
        uint2* dst = reinterpret_cast<uint2*>(sh4);
        #pragma unroll
        for (int i = 0; i < 32; ++i) {
            const int f = tid + 256 * i;      // float4 index within 32x1024 slice
            const float4 v = src[f];
            dst[f] = make_uint2(pk2(v.x, v.y), pk2(v.z, v.w));
        }
    }
    __syncthreads();

    const int wid  = tid >> 6;
    const int lane = tid & 63;
    const int t0   = base + wid * 2;
    const int t1   = t0 + 1;
    if (t0 >= n_e) return;                    // uniform per wave; no barriers after
    const bool has1 = (t1 < n_e);
    const int tokA = list[e * ntok + t0];
    const int tokB = has1 ? list[e * ntok + t1] : tokA;

    // ---- load h rows (lane owns dims [lane*16, lane*16+16)) as f16x2 ----
    const float4* h4 = reinterpret_cast<const float4*>(h);
    unsigned hA[8], hB[8];
    #pragma unroll
    for (int i = 0; i < 4; ++i) {
        const float4 a = h4[(size_t)tokA * 256 + lane * 4 + i];
        hA[2 * i]     = pk2(a.x, a.y);
        hA[2 * i + 1] = pk2(a.z, a.w);
        const float4 b = h4[(size_t)tokB * 256 + lane * 4 + i];
        hB[2 * i]     = pk2(b.x, b.y);
        hB[2 * i + 1] = pk2(b.z, b.w);
    }

    // ---- scores: p[j] = dot(h, row_j), f32 accum via v_dot2_f32_f16 ----
    float pA[TOPK], pB[TOPK];
    #pragma unroll
    for (int j = 0; j < TOPK; ++j) {
        const uint4 va = sh4[j * 128 + lane * 2];
        const uint4 vb = sh4[j * 128 + lane * 2 + 1];
        float a = 0.f, b = 0.f;
        a = fdot2u(hA[0], va.x, a); a = fdot2u(hA[1], va.y, a);
        a = fdot2u(hA[2], va.z, a); a = fdot2u(hA[3], va.w, a);
        a = fdot2u(hA[4], vb.x, a); a = fdot2u(hA[5], vb.y, a);
        a = fdot2u(hA[6], vb.z, a); a = fdot2u(hA[7], vb.w, a);
        b = fdot2u(hB[0], va.x, b); b = fdot2u(hB[1], va.y, b);
        b = fdot2u(hB[2], va.z, b); b = fdot2u(hB[3], va.w, b);
        b = fdot2u(hB[4], vb.x, b); b = fdot2u(hB[5], vb.y, b);
        b = fdot2u(hB[6], vb.z, b); b = fdot2u(hB[7], vb.w, b);
        pA[j] = a; pB[j] = b;
    }

    // ---- full butterfly: every lane ends with all 32 sums ----
    #pragma unroll
    for (int m = 1; m < 64; m <<= 1) {
        #pragma unroll
        for (int j = 0; j < TOPK; ++j) {
            pA[j] += __shfl_xor(pA[j], m);
            pB[j] += __shfl_xor(pB[j], m);
        }
    }

    // ---- softmax over 32 (scale 1/sqrt(1024) folded into exp arg) ----
    constexpr float inv32 = 1.f / 32.f;
    float mA = -INFINITY, mB = -INFINITY;
    #pragma unroll
    for (int j = 0; j < TOPK; ++j) { mA = fmaxf(mA, pA[j]); mB = fmaxf(mB, pB[j]); }
    float sA = 0.f, sB = 0.f;
    #pragma unroll
    for (int j = 0; j < TOPK; ++j) {
        pA[j] = __expf((pA[j] - mA) * inv32); sA += pA[j];
        pB[j] = __expf((pB[j] - mB) * inv32); sB += pB[j];
    }
    const float iA = 1.f / sA, iB = 1.f / sB;

    // ---- weighted sum in packed f16 (v_pk_fma_f16), f32 out ----
    __half2 aA[8], aB[8];
    #pragma unroll
    for (int i = 0; i < 8; ++i) { aA[i] = __float2half2_rn(0.f); aB[i] = __float2half2_rn(0.f); }
    #pragma unroll
    for (int j = 0; j < TOPK; ++j) {
        const uint4 va = sh4[j * 128 + lane * 2];
        const uint4 vb = sh4[j * 128 + lane * 2 + 1];
        const __half2 wA = __float2half2_rn(pA[j] * iA);
        const __half2 wB = __float2half2_rn(pB[j] * iB);
        aA[0] = __hfma2(wA, as_hh2(va.x), aA[0]);
        aA[1] = __hfma2(wA, as_hh2(va.y), aA[1]);
        aA[2] = __hfma2(wA, as_hh2(va.z), aA[2]);
        aA[3] = __hfma2(wA, as_hh2(va.w), aA[3]);
        aA[4] = __hfma2(wA, as_hh2(vb.x), aA[4]);
        aA[5] = __hfma2(wA, as_hh2(vb.y), aA[5]);
        aA[6] = __hfma2(wA, as_hh2(vb.z), aA[6]);
        aA[7] = __hfma2(wA, as_hh2(vb.w), aA[7]);
        aB[0] = __hfma2(wB, as_hh2(va.x), aB[0]);
        aB[1] = __hfma2(wB, as_hh2(va.y), aB[1]);
        aB[2] = __hfma2(wB, as_hh2(va.z), aB[2]);
        aB[3] = __hfma2(wB, as_hh2(va.w), aB[3]);
        aB[4] = __hfma2(wB, as_hh2(vb.x), aB[4]);
        aB[5] = __hfma2(wB, as_hh2(vb.y), aB[5]);
        aB[6] = __hfma2(wB, as_hh2(vb.z), aB[6]);
        aB[7] = __hfma2(wB, as_hh2(vb.w), aB[7]);
    }

    float4* o4 = reinterpret_cast<float4*>(out_res);
    #pragma unroll
    for (int i = 0; i < 4; ++i) {
        float4 o;
        o.x = __low2float(aA[2 * i]);     o.y = __high2float(aA[2 * i]);
        o.z = __low2float(aA[2 * i + 1]); o.w = __high2float(aA[2 * i + 1]);
        o4[(size_t)tokA * 256 + lane * 4 + i] = o;
    }
    if (has1) {
        #pragma unroll
        for (int i = 0; i < 4; ++i) {
            float4 o;
            o.x = __low2float(aB[2 * i]);     o.y = __high2float(aB[2 * i]);
            o.z = __low2float(aB[2 * i + 1]); o.w = __high2float(aB[2 * i + 1]);
            o4[(size_t)tokB * 256 + lane * 4 + i] = o;
        }
    }
}

extern "C" void kernel_launch(void* const* d_in, const int* in_sizes, int n_in,
                              void* d_out, int out_size, void* d_ws, size_t ws_size,
                              hipStream_t stream) {
    const float* h   = (const float*)d_in[0];
    const float* lts = (const float*)d_in[1];
    const float* Wr  = (const float*)d_in[2];
    const float* br  = (const float*)d_in[3];

    const int ntok = in_sizes[0] / D;            // b*t = 4096
    float* out_res = (float*)d_out;              // (b,t,d)
    float* out_ew  = out_res + (size_t)ntok * D; // (b,t,NEXP)

    int* cnt  = (int*)d_ws;                      // [NEXP]
    int* list = cnt + NEXP;                      // [NEXP][ntok]

    (void)hipMemsetAsync(cnt, 0, NEXP * sizeof(int), stream);

    router_kernel<<<(ntok + 3) / 4, 256, 0, stream>>>(h, Wr, br, out_ew, cnt, list, ntok);

    const int chunks = (ntok + TB - 1) / TB;     // 512
    attn_kernel<<<NEXP * chunks, 256, 0, stream>>>(h, lts, cnt, list, out_res, ntok, chunks);
}

// Round 4
// 48.952 us; speedup vs baseline: 2.3370x; 2.3370x over previous
//
#include <hip/hip_runtime.h>
#include <hip/hip_fp16.h>
#include <math.h>

constexpr int D    = 1024;
constexpr int NEXP = 4;
constexpr int TOPK = 32;
constexpr int EPP  = 2048;   // entries per expert
constexpr int TB   = 8;      // tokens per attn chunk (2 per wave, 4 waves)
constexpr int BPE  = 128;    // attn blocks per expert
constexpr int CSTR = 16;     // counter padding in ints (64B cachelines)

using pk_t = decltype(__builtin_amdgcn_cvt_pkrtz(0.f, 0.f));
__device__ __forceinline__ unsigned pk2(float a, float b) {
    return __builtin_bit_cast(unsigned, __builtin_amdgcn_cvt_pkrtz(a, b));
}
__device__ __forceinline__ __half2 as_hh2(unsigned u) { return __builtin_bit_cast(__half2, u); }
__device__ __forceinline__ float fdot2u(unsigned a, unsigned b, float c) {
    return __builtin_amdgcn_fdot2(__builtin_bit_cast(pk_t, a),
                                  __builtin_bit_cast(pk_t, b), c, false);
}

// ---------------- Phase 1: router ----------------
// 1024 threads = 16 waves, 2 tokens/wave -> 32 tokens/block.
// LDS-aggregated counts: 4 padded global atomics per block (vs 1 per token).
__global__ __launch_bounds__(1024) void router_kernel(
    const float* __restrict__ h, const float* __restrict__ Wr,
    const float* __restrict__ br,
    float* __restrict__ out_ew, int* __restrict__ cnt, int* __restrict__ list,
    int ntok)
{
    const int tid  = threadIdx.x;
    const int wid  = tid >> 6;
    const int lane = tid & 63;

    __shared__ int lds_cnt[NEXP];
    __shared__ int lds_base[NEXP];
    if (tid < NEXP) lds_cnt[tid] = 0;
    __syncthreads();

    const float4* h4 = reinterpret_cast<const float4*>(h);
    const float4* w4 = reinterpret_cast<const float4*>(Wr);

    float4 wf[NEXP][4];
    #pragma unroll
    for (int e = 0; e < NEXP; ++e)
        #pragma unroll
        for (int i = 0; i < 4; ++i)
            wf[e][i] = w4[e * 256 + lane + 64 * i];
    const float bb0 = br[0], bb1 = br[1], bb2 = br[2], bb3 = br[3];

    int mybi[2] = {0, 0}, myrank[2] = {0, 0}, mytok[2] = {-1, -1};

    #pragma unroll
    for (int t = 0; t < 2; ++t) {
        const int tok = blockIdx.x * 32 + wid * 2 + t;
        if (tok < ntok) {
            float acc[NEXP] = {0.f, 0.f, 0.f, 0.f};
            #pragma unroll
            for (int i = 0; i < 4; ++i) {
                const float4 a = h4[(size_t)tok * 256 + lane + 64 * i];
                #pragma unroll
                for (int e = 0; e < NEXP; ++e)
                    acc[e] += a.x * wf[e][i].x + a.y * wf[e][i].y
                            + a.z * wf[e][i].z + a.w * wf[e][i].w;
            }
            #pragma unroll
            for (int m = 1; m < 64; m <<= 1)
                #pragma unroll
                for (int e = 0; e < NEXP; ++e) acc[e] += __shfl_xor(acc[e], m);

            const float l0 = acc[0] + bb0, l1 = acc[1] + bb1,
                        l2 = acc[2] + bb2, l3 = acc[3] + bb3;
            const float lm = fmaxf(fmaxf(l0, l1), fmaxf(l2, l3));
            const float e0 = __expf(l0 - lm), e1 = __expf(l1 - lm),
                        e2 = __expf(l2 - lm), e3 = __expf(l3 - lm);
            const float einv = 1.f / (e0 + e1 + e2 + e3);
            if (lane < NEXP) {
                const float ev = (lane == 0) ? e0 : (lane == 1) ? e1 : (lane == 2) ? e2 : e3;
                out_ew[(size_t)tok * NEXP + lane] = ev * einv;
            }
            int bi = 0; float bv = l0;
            if (l1 > bv) { bv = l1; bi = 1; }
            if (l2 > bv) { bv = l2; bi = 2; }
            if (l3 > bv) { bv = l3; bi = 3; }
            if (lane == 0) {
                mybi[t] = bi; mytok[t] = tok;
                myrank[t] = atomicAdd(&lds_cnt[bi], 1);
            }
        }
    }
    __syncthreads();
    if (tid < NEXP) lds_base[tid] = atomicAdd(&cnt[tid * CSTR], lds_cnt[tid]);
    __syncthreads();
    #pragma unroll
    for (int t = 0; t < 2; ++t)
        if (lane == 0 && mytok[t] >= 0)
            list[(size_t)mybi[t] * ntok + lds_base[mybi[t]] + myrank[t]] = mytok[t];
}

// ---------------- Phase 2: grouped attention ----------------
// 512 blocks (128/expert), grid-stride over chunks. Slice staged once per
// block, f16, split-half row layout (conflict-free ds_read_b128).
__global__ __launch_bounds__(256) void attn_kernel(
    const float* __restrict__ h, const float* __restrict__ lts,
    const int* __restrict__ cnt, const int* __restrict__ list,
    float* __restrict__ out_res, int ntok)
{
    const int e   = blockIdx.x >> 7;          // / BPE
    const int b0  = blockIdx.x & (BPE - 1);
    const int n_e = cnt[e * CSTR];
    if (b0 * TB >= n_e) return;               // uniform per block, before barrier

    const int tid = threadIdx.x;
    __shared__ unsigned char lds[32 * 2048];  // 64 KB

    // stage slice: row r -> half0 = dims[16l..16l+8) per lane l, half1 = rest
    {
        const float4* src = reinterpret_cast<const float4*>(lts + (size_t)e * EPP * D);
        #pragma unroll
        for (int i = 0; i < 32; ++i) {
            const int f  = tid + 256 * i;
            const float4 v = src[f];
            const int row = f >> 8;
            const int d0  = (f & 255) << 2;
            const int dst = row * 2048 + ((d0 & 8) ? 1024 : 0)
                          + ((d0 >> 4) << 4) + ((d0 & 7) << 1);
            *reinterpret_cast<uint2*>(lds + dst) = make_uint2(pk2(v.x, v.y), pk2(v.z, v.w));
        }
    }
    __syncthreads();

    const int wid = tid >> 6, lane = tid & 63;
    const float4* h4 = reinterpret_cast<const float4*>(h);
    float4* o4 = reinterpret_cast<float4*>(out_res);

    for (int c = b0; c * TB < n_e; c += BPE) {
        const int t0 = c * TB + wid * 2;
        if (t0 >= n_e) continue;              // no barriers below: safe
        const bool has1 = (t0 + 1 < n_e);
        const int tokA = list[(size_t)e * ntok + t0];
        const int tokB = has1 ? list[(size_t)e * ntok + t0 + 1] : tokA;

        // h rows: lane owns dims [16*lane, 16*lane+16)
        unsigned hA[8], hB[8];
        #pragma unroll
        for (int i = 0; i < 4; ++i) {
            const float4 a = h4[(size_t)tokA * 256 + lane * 4 + i];
            hA[2 * i] = pk2(a.x, a.y); hA[2 * i + 1] = pk2(a.z, a.w);
            const float4 b = h4[(size_t)tokB * 256 + lane * 4 + i];
            hB[2 * i] = pk2(b.x, b.y); hB[2 * i + 1] = pk2(b.z, b.w);
        }

        // scores: per-lane partials over its 16 dims; p[0..31]=A, p[32..63]=B
        float p[64];
        #pragma unroll
        for (int j = 0; j < 32; ++j) {
            const uint4 va = *reinterpret_cast<const uint4*>(lds + j * 2048 + lane * 16);
            const uint4 vb = *reinterpret_cast<const uint4*>(lds + j * 2048 + 1024 + lane * 16);
            float a = 0.f, b = 0.f;
            a = fdot2u(hA[0], va.x, a); a = fdot2u(hA[1], va.y, a);
            a = fdot2u(hA[2], va.z, a); a = fdot2u(hA[3], va.w, a);
            a = fdot2u(hA[4], vb.x, a); a = fdot2u(hA[5], vb.y, a);
            a = fdot2u(hA[6], vb.z, a); a = fdot2u(hA[7], vb.w, a);
            b = fdot2u(hB[0], va.x, b); b = fdot2u(hB[1], va.y, b);
            b = fdot2u(hB[2], va.z, b); b = fdot2u(hB[3], va.w, b);
            b = fdot2u(hB[4], vb.x, b); b = fdot2u(hB[5], vb.y, b);
            b = fdot2u(hB[6], vb.z, b); b = fdot2u(hB[7], vb.w, b);
            p[j] = a; p[j + 32] = b;
        }

        // fold-reduce: 64 values x 64 lanes -> lane L holds total of value L
        #pragma unroll
        for (int s = 0; s < 6; ++s) {
            const int m = 32 >> s;            // mask == half size
            #pragma unroll
            for (int i = 0; i < (32 >> s); ++i) {
                const bool hib  = (lane & m) != 0;
                const float send = hib ? p[i] : p[i + (32 >> s)];
                const float recv = __shfl_xor(send, m);
                p[i] = (hib ? p[i + (32 >> s)] : p[i]) + recv;
            }
        }

        // distributed softmax: lanes 0..31 = token A scores, 32..63 = token B
        const float x = p[0] * 0.03125f;      // / sqrt(1024)
        float mx = x;
        #pragma unroll
        for (int m = 16; m >= 1; m >>= 1) mx = fmaxf(mx, __shfl_xor(mx, m));
        const float ex = __expf(x - mx);
        float sm = ex;
        #pragma unroll
        for (int m = 16; m >= 1; m >>= 1) sm += __shfl_xor(sm, m);
        const float sOth = __shfl_xor(sm, 32);
        const float invA = 1.f / ((lane < 32) ? sm : sOth);
        const float invB = 1.f / ((lane < 32) ? sOth : sm);

        // weighted sum: broadcast weights via readlane, accumulate f16x2
        __half2 aA[8], aB[8];
        #pragma unroll
        for (int i = 0; i < 8; ++i) {
            aA[i] = __float2half2_rn(0.f);
            aB[i] = __float2half2_rn(0.f);
        }
        #pragma unroll
        for (int j = 0; j < 32; ++j) {
            const uint4 va = *reinterpret_cast<const uint4*>(lds + j * 2048 + lane * 16);
            const uint4 vb = *reinterpret_cast<const uint4*>(lds + j * 2048 + 1024 + lane * 16);
            const __half2 wA = __float2half2_rn(__shfl(ex, j));
            const __half2 wB = __float2half2_rn(__shfl(ex, j + 32));
            aA[0] = __hfma2(wA, as_hh2(va.x), aA[0]);
            aA[1] = __hfma2(wA, as_hh2(va.y), aA[1]);
            aA[2] = __hfma2(wA, as_hh2(va.z), aA[2]);
            aA[3] = __hfma2(wA, as_hh2(va.w), aA[3]);
            aA[4] = __hfma2(wA, as_hh2(vb.x), aA[4]);
            aA[5] = __hfma2(wA, as_hh2(vb.y), aA[5]);
            aA[6] = __hfma2(wA, as_hh2(vb.z), aA[6]);
            aA[7] = __hfma2(wA, as_hh2(vb.w), aA[7]);
            aB[0] = __hfma2(wB, as_hh2(va.x), aB[0]);
            aB[1] = __hfma2(wB, as_hh2(va.y), aB[1]);
            aB[2] = __hfma2(wB, as_hh2(va.z), aB[2]);
            aB[3] = __hfma2(wB, as_hh2(va.w), aB[3]);
            aB[4] = __hfma2(wB, as_hh2(vb.x), aB[4]);
            aB[5] = __hfma2(wB, as_hh2(vb.y), aB[5]);
            aB[6] = __hfma2(wB, as_hh2(vb.z), aB[6]);
            aB[7] = __hfma2(wB, as_hh2(vb.w), aB[7]);
        }

        #pragma unroll
        for (int i = 0; i < 4; ++i) {
            float4 o;
            o.x = __low2float(aA[2 * i]) * invA;
            o.y = __high2float(aA[2 * i]) * invA;
            o.z = __low2float(aA[2 * i + 1]) * invA;
            o.w = __high2float(aA[2 * i + 1]) * invA;
            o4[(size_t)tokA * 256 + lane * 4 + i] = o;
        }
        if (has1) {
            #pragma unroll
            for (int i = 0; i < 4; ++i) {
                float4 o;
                o.x = __low2float(aB[2 * i]) * invB;
                o.y = __high2float(aB[2 * i]) * invB;
                o.z = __low2float(aB[2 * i + 1]) * invB;
                o.w = __high2float(aB[2 * i + 1]) * invB;
                o4[(size_t)tokB * 256 + lane * 4 + i] = o;
            }
        }
    }
}

extern "C" void kernel_launch(void* const* d_in, const int* in_sizes, int n_in,
                              void* d_out, int out_size, void* d_ws, size_t ws_size,
                              hipStream_t stream) {
    const float* h   = (const float*)d_in[0];
    const float* lts = (const float*)d_in[1];
    const float* Wr  = (const float*)d_in[2];
    const float* br  = (const float*)d_in[3];

    const int ntok = in_sizes[0] / D;            // b*t = 4096
    float* out_res = (float*)d_out;              // (b,t,d)
    float* out_ew  = out_res + (size_t)ntok * D; // (b,t,NEXP)

    int* cnt  = (int*)d_ws;                      // [NEXP * CSTR] padded counters
    int* list = cnt + NEXP * CSTR;               // [NEXP][ntok]

    (void)hipMemsetAsync(cnt, 0, NEXP * CSTR * sizeof(int), stream);

    const int rblocks = (ntok + 31) / 32;
    router_kernel<<<rblocks, 1024, 0, stream>>>(h, Wr, br, out_ew, cnt, list, ntok);

    attn_kernel<<<NEXP * BPE, 256, 0, stream>>>(h, lts, cnt, list, out_res, ntok);
}